// Round 2
// baseline (3319.761 us; speedup 1.0000x reference)
//
#include <hip/hip_runtime.h>
#include <hip/hip_bf16.h>

// Problem: Berger-style max-tree (component tree) per channel, 64x64x3 input.
// Outputs (float32): parents [3,4096] then altitudes [3,4096] = 24576 elems.
//
// Hardcoded H=W=64 (matches setup_inputs; harness always uses it).

#define N_PIX 4096
#define CH 3

// ---------------------------------------------------------------------------
// Kernel 1: stable descending rank -> order array (exact argsort(-f) stable)
// rank(p) = #{q: f[q] > f[p]} + #{q: f[q]==f[p] && q < p}
// 48 blocks = 3 channels x 16 segments of 256 pixels; 256 threads each.
// ---------------------------------------------------------------------------
__global__ __launch_bounds__(256) void ct_rank(const float* __restrict__ vw,
                                               int* __restrict__ order_g) {
    __shared__ __align__(16) float vals[N_PIX];
    const int c   = blockIdx.x >> 4;
    const int seg = blockIdx.x & 15;
    const int tid = threadIdx.x;
    for (int i = tid; i < N_PIX; i += 256) vals[i] = vw[i * CH + c];
    __syncthreads();

    const int   p  = (seg << 8) + tid;
    const float vp = vals[p];
    int cnt = 0;
    const float4* v4 = reinterpret_cast<const float4*>(vals);
#pragma unroll 4
    for (int j4 = 0; j4 < N_PIX / 4; ++j4) {
        float4 q = v4[j4];
        int j = j4 << 2;
        cnt += (q.x > vp) || ((q.x == vp) && (j     < p));
        cnt += (q.y > vp) || ((q.y == vp) && (j + 1 < p));
        cnt += (q.z > vp) || ((q.z == vp) && (j + 2 < p));
        cnt += (q.w > vp) || ((q.w == vp) && (j + 3 < p));
    }
    order_g[(c << 12) + cnt] = p;
}

// ---------------------------------------------------------------------------
// Kernel 2: serial union-find in processing order, one wave per channel.
// zpar[x] == -1  <=>  not yet processed (replaces proc[] -> one less LDS read).
// Lanes 0-3 handle the 4 neighbors IN PARALLEL: all finds observe the
// pre-update zpar state, reach the true pre-merge roots, and every union
// write stores the same value p -> equivalent to the sequential inner loop.
// Path-halving during find + pointing merged neighbors at p keeps chains short
// (zpar is internal state; any forward-compression preserves semantics).
// ---------------------------------------------------------------------------
__global__ __launch_bounds__(64) void ct_union(const int* __restrict__ order_g,
                                               int* __restrict__ parent_g) {
    __shared__ int order_s[N_PIX];
    __shared__ int zpar_s[N_PIX];
    __shared__ int parent_s[N_PIX];
    const int c    = blockIdx.x;
    const int lane = threadIdx.x;

    for (int i = lane; i < N_PIX; i += 64) {
        order_s[i] = order_g[(c << 12) + i];
        zpar_s[i]  = -1;
    }
    __syncthreads();

    volatile int* zpar   = zpar_s;
    volatile int* parent = parent_s;

    int p = order_s[0];
    for (int i = 0; i < N_PIX; ++i) {
        // prefetch next p so its LDS latency overlaps this iteration's chain
        int pn = order_s[(i + 1) & (N_PIX - 1)];

        if (lane == 4) zpar[p]   = p;   // mark processed (n != p, no interact)
        if (lane == 5) parent[p] = p;

        const int row = p >> 6, col = p & 63;
        int n; bool valid;
        if      (lane == 0) { n = p - 64; valid = row > 0;  }
        else if (lane == 1) { n = p + 64; valid = row < 63; }
        else if (lane == 2) { n = p - 1;  valid = col > 0;  }
        else if (lane == 3) { n = p + 1;  valid = col < 63; }
        else                { n = p;      valid = false;    }
        const int nc = n < 0 ? 0 : (n > N_PIX - 1 ? N_PIX - 1 : n);

        const int z0 = zpar[nc];
        const bool ok = valid && (z0 >= 0);

        int r = p;
        if (ok) {
            int y = nc, z = z0;
            while (z != y) {            // find root with path-halving
                int w = zpar[z];
                zpar[y] = w;
                y = z;
                z = w;
            }
            r = y;
        }
        if (ok && r != p) { parent[r] = p; zpar[r] = p; }
        if (ok)           { zpar[nc] = p; }   // n's component root is now p

        p = pn;
    }
    __syncthreads();
    for (int i = lane; i < N_PIX; i += 64)
        parent_g[(c << 12) + i] = parent_s[i];
}

// ---------------------------------------------------------------------------
// Kernel 3: canonicalization (parallel closed form) + outputs (float32).
// Final parent[p] = h(parent_u[p]) where h(x) climbs parent_u while the
// parent has equal altitude (and is not the root). Derivation: the reference
// reverse-order canon pass satisfies g(p) = h(parent_u[p]) with
// h(x) = (x root || f[parent_u[x]] != f[x]) ? x : h(parent_u[x]).
// ---------------------------------------------------------------------------
__global__ __launch_bounds__(256) void ct_canon(const float* __restrict__ vw,
                                                const int* __restrict__ parent_g,
                                                float* __restrict__ out) {
    const int gid = blockIdx.x * 256 + threadIdx.x;   // 0 .. 3*4096-1
    const int c = gid >> 12;
    const int p = gid & (N_PIX - 1);
    const int* par = parent_g + (c << 12);

    int q = par[p];
    float fq = vw[q * CH + c];
    for (;;) {
        int qp = par[q];
        if (qp == q) break;                 // root
        float fqp = vw[qp * CH + c];
        if (fqp != fq) break;               // altitude changes -> canonical
        q = qp;
    }
    out[gid] = (float)q;
    out[CH * N_PIX + gid] = vw[p * CH + c];
}

extern "C" void kernel_launch(void* const* d_in, const int* in_sizes, int n_in,
                              void* d_out, int out_size, void* d_ws, size_t ws_size,
                              hipStream_t stream) {
    const float* vw = (const float*)d_in[0];
    float* out = (float*)d_out;

    int* order_g  = (int*)d_ws;                 // 3*4096 ints
    int* parent_g = order_g + CH * N_PIX;       // 3*4096 ints

    ct_rank <<<48, 256, 0, stream>>>(vw, order_g);
    ct_union<<<CH, 64, 0, stream>>>(order_g, parent_g);
    ct_canon<<<48, 256, 0, stream>>>(vw, parent_g, out);
}